// Round 1
// baseline (21.853 us; speedup 1.0000x reference)
//
#include <hip/hip_runtime.h>
#include <math.h>

#define TWO_PI_F 6.2831853071795864769f

// One wave (64 lanes) per event. obs_t is sorted -> history window is a
// contiguous range found by binary search. Fused exponential per pair.
__global__ __launch_bounds__(256) void etas_main(
    const float* __restrict__ t, const float* __restrict__ xy,
    const float* __restrict__ pL0, const float* __restrict__ pC,
    const float* __restrict__ pBe, const float* __restrict__ pSx,
    const float* __restrict__ pSy, const int* __restrict__ pnd,
    const int* __restrict__ pkpt,
    float* __restrict__ partL, float* __restrict__ partF, int n)
{
    const int wave = threadIdx.x >> 6;
    const int lane = threadIdx.x & 63;
    const int ev   = blockIdx.x * 4 + wave;

    __shared__ float sL[4], sF[4];

    float logl = 0.f, fc = 0.f;
    if (ev < n) {
        const float L0 = pL0[0], C = pC[0], Beta = pBe[0];
        const float Sx = pSx[0], Sy = pSy[0];
        const int   nd = pnd[0], kpt = pkpt[0];
        const float ti = t[ev];
        const float xi = xy[2 * ev], yi = xy[2 * ev + 1];

        // lo = lower_bound(t, ti - kpt); hi = lower_bound(t, ti)
        const float tlo = ti - (float)kpt;
        int lo, hi;
        { int l = 0, r = n; while (l < r) { int m = (l + r) >> 1; if (t[m] < tlo) l = m + 1; else r = m; } lo = l; }
        { int l = 0, r = n; while (l < r) { int m = (l + r) >> 1; if (t[m] < ti)  l = m + 1; else r = m; } hi = l; }

        const float iSx2 = 1.f / (Sx * Sx), iSy2 = 1.f / (Sy * Sy);
        float acc = 0.f;
        for (int j = lo + lane; j < hi; j += 64) {
            float dt  = ti - t[j];          // integer-valued, in (0, kpt]
            float idt = 1.f / dt;
            float dx  = xi - xy[2 * j];
            float dy  = yi - xy[2 * j + 1];
            float arg = -Beta * dt - 0.5f * idt * (dx * dx * iSx2 + dy * dy * iSy2);
            acc += idt * __expf(arg);
        }
        // wave reduction (64 lanes)
        for (int off = 32; off > 0; off >>= 1) acc += __shfl_down(acc, off, 64);

        if (lane == 0) {
            float lam = (ti <= 1.0f) ? L0 : (acc * (C / (TWO_PI_F * Sx * Sy)));
            logl = logf(lam);
            // F contribution of this event: C * sum_{k=1..min(kpt, nd - day)} exp(-Beta*k)
            int m = nd - (int)ti; if (m > kpt) m = kpt;
            float s = 0.f;
            for (int k = 1; k <= m; ++k) s += __expf(-Beta * (float)k);
            fc = C * s;
        }
    }
    if (lane == 0) { sL[wave] = logl; sF[wave] = fc; }
    __syncthreads();
    if (threadIdx.x == 0) {
        partL[blockIdx.x] = sL[0] + sL[1] + sL[2] + sL[3];
        partF[blockIdx.x] = sF[0] + sF[1] + sF[2] + sF[3];
    }
}

__global__ __launch_bounds__(256) void etas_reduce(
    const float* __restrict__ partL, const float* __restrict__ partF, int nb,
    const float* __restrict__ pL0, const float* __restrict__ pArea,
    const int* __restrict__ pnd, float* __restrict__ out)
{
    __shared__ float sA[256], sB[256];
    float a = 0.f, b = 0.f;
    for (int i = threadIdx.x; i < nb; i += 256) { a += partL[i]; b += partF[i]; }
    sA[threadIdx.x] = a; sB[threadIdx.x] = b;
    __syncthreads();
    for (int s = 128; s > 0; s >>= 1) {
        if (threadIdx.x < s) {
            sA[threadIdx.x] += sA[threadIdx.x + s];
            sB[threadIdx.x] += sB[threadIdx.x + s];
        }
        __syncthreads();
    }
    if (threadIdx.x == 0) {
        float lams1 = sA[0];
        float lams2 = pL0[0] * pArea[0] * (float)pnd[0] + sB[0];
        out[0] = lams1 - lams2;   // loglik
        out[1] = lams1;
        out[2] = lams2;
    }
}

extern "C" void kernel_launch(void* const* d_in, const int* in_sizes, int n_in,
                              void* d_out, int out_size, void* d_ws, size_t ws_size,
                              hipStream_t stream)
{
    const float* obs_t  = (const float*)d_in[0];
    const float* obs_xy = (const float*)d_in[1];
    const float* pL0    = (const float*)d_in[2];
    const float* pC     = (const float*)d_in[3];
    const float* pBe    = (const float*)d_in[4];
    const float* pSx    = (const float*)d_in[5];
    const float* pSy    = (const float*)d_in[6];
    const float* pArea  = (const float*)d_in[7];
    const int*   pnd    = (const int*)d_in[8];
    const int*   pkpt   = (const int*)d_in[9];

    const int n  = in_sizes[0];
    const int nb = (n + 3) / 4;          // 4 events (waves) per block

    float* partL = (float*)d_ws;         // [nb]
    float* partF = partL + nb;           // [nb]

    etas_main<<<nb, 256, 0, stream>>>(obs_t, obs_xy, pL0, pC, pBe, pSx, pSy,
                                      pnd, pkpt, partL, partF, n);
    etas_reduce<<<1, 256, 0, stream>>>(partL, partF, nb, pL0, pArea, pnd,
                                       (float*)d_out);
}